// Round 7
// baseline (21269.214 us; speedup 1.0000x reference)
//
#include <hip/hip_runtime.h>
#include <math.h>

#define B_ 128
#define T_ 128
#define D_ 128
#define H_ 512
#define M_ 32

// ---- workspace layout (float offsets) ----
#define OFF_H    0        // [128][512]   h_{t-1} / h_t
#define OFF_HC   65536    // [128][1024]  h_tilde | c
#define OFF_S    196608   // [128][512]   s_t
#define OFF_PRE  262144   // [128][2560]  gate preactivations
#define OFF_Q    589824   // [128][512]   q
#define OFF_HW   655360   // [128][512]   h_tilde @ W_h
#define OFF_E    720896   // [128][512]   e_t
#define OFF_BUF  786432   // [128][32][512] ring of h
#define OFF_BUFW 2883584  // [128][32][512] ring of h@Wah

struct P {
    float* ws;
    const float *x, *dlt, *g;
    const float *Wsh, *Wsx, *Wst, *bs;
    const float *Wh, *Wx, *Ws, *bg;
    const float *Waq, *Wah, *ba, *vt;
    const float *W_h, *W_e, *W_g, *bh;
    const float *Wcls, *bcls;
    float* out;
};

__device__ __forceinline__ float sigf(float x) { return 1.0f / (1.0f + expf(-x)); }

// Shared GEMM geometry: C[32,64] per block, BK=32, 256 threads, 2x4 micro-tile.
// Index helpers are recomputed identically in each kernel (no templates:
// ROCm 7.2 clang-22 segfaults on templated __global__ + <N><<< launches).

// GEMM 1: A=[h | x_t] (K=640), B = [Wsh;Wsx] | [Wh;Wx]x5 | [Wah;0] (N=3584)
// -> s_t (tanh, +d*Wst+bs), pre (raw), bufW slot (t-1) for h_{t-1}
__global__ __launch_bounds__(256) void k_g1(P p, int t)
{
    __shared__ float As[32][36];
    __shared__ float Bs[32][64];
    const int tid  = threadIdx.x;
    const int nblk = blockIdx.x, mblk = blockIdx.y;
    float acc[2][4] = {};
    const int m0   = (tid >> 4) << 1;
    const int n0   = (tid & 15) << 2;
    const int arow = tid >> 3;
    const int acol = (tid & 7) << 2;
    const int brow = tid >> 4;
    const int bcol = (tid & 15) << 2;
    const int mg   = mblk * 32 + arow;
    const float* hsrc = p.ws + OFF_H;

    for (int k0 = 0; k0 < 640; k0 += 32) {
        {
            int kg = k0 + acol;
            float4 av;
            if (kg < 512) av = *(const float4*)(hsrc + (size_t)mg * 512 + kg);
            else          av = *(const float4*)(p.x + ((size_t)mg * T_ + t) * D_ + (kg - 512));
            *(float4*)&As[arow][acol] = av;
        }
        #pragma unroll
        for (int rr = 0; rr < 2; ++rr) {
            int krow = k0 + brow + rr * 16;
            int col  = nblk * 64 + bcol;
            float4 bv;
            if (col < 512) {
                const float* s = (krow < 512) ? p.Wsh + (size_t)krow * 512 + col
                                              : p.Wsx + (size_t)(krow - 512) * 512 + col;
                bv = *(const float4*)s;
            } else if (col < 3072) {
                int gg = (col - 512) >> 9, j = (col - 512) & 511;
                const float* s = (krow < 512) ? p.Wh + ((size_t)gg * 512 + krow) * 512 + j
                                              : p.Wx + ((size_t)gg * 128 + (krow - 512)) * 512 + j;
                bv = *(const float4*)s;
            } else {
                if (krow < 512) bv = *(const float4*)(p.Wah + (size_t)krow * 512 + (col - 3072));
                else            bv = make_float4(0.f, 0.f, 0.f, 0.f);
            }
            *(float4*)&Bs[brow + rr * 16][bcol] = bv;
        }
        __syncthreads();
        #pragma unroll
        for (int kk = 0; kk < 32; ++kk) {
            float a0 = As[m0][kk], a1 = As[m0 + 1][kk];
            float4 bv = *(float4*)&Bs[kk][n0];
            acc[0][0] = fmaf(a0, bv.x, acc[0][0]);
            acc[0][1] = fmaf(a0, bv.y, acc[0][1]);
            acc[0][2] = fmaf(a0, bv.z, acc[0][2]);
            acc[0][3] = fmaf(a0, bv.w, acc[0][3]);
            acc[1][0] = fmaf(a1, bv.x, acc[1][0]);
            acc[1][1] = fmaf(a1, bv.y, acc[1][1]);
            acc[1][2] = fmaf(a1, bv.z, acc[1][2]);
            acc[1][3] = fmaf(a1, bv.w, acc[1][3]);
        }
        __syncthreads();
    }
    #pragma unroll
    for (int r = 0; r < 2; ++r) {
        int b = mblk * 32 + m0 + r;
        #pragma unroll
        for (int j = 0; j < 4; ++j) {
            int n = nblk * 64 + n0 + j;
            float v = acc[r][j];
            if (n < 512) {
                float sv = tanhf(v + p.dlt[(size_t)b * T_ + t] * p.Wst[n] + p.bs[n]);
                p.ws[OFF_S + (size_t)b * H_ + n] = sv;
            } else if (n < 3072) {
                p.ws[OFF_PRE + (size_t)b * 2560 + (n - 512)] = v;
            } else if (t > 0) {
                int slot = (t - 1) & (M_ - 1);
                p.ws[OFF_BUFW + ((size_t)b * M_ + slot) * H_ + (n - 3072)] = v;
            }
        }
    }
}

// GEMM 2: A=s_t (K=512), B=Ws[z] (grid.z), pre += acc + bg
__global__ __launch_bounds__(256) void k_g2(P p, int t)
{
    __shared__ float As[32][36];
    __shared__ float Bs[32][64];
    const int tid  = threadIdx.x;
    const int nblk = blockIdx.x, mblk = blockIdx.y;
    const int gz   = blockIdx.z;
    float acc[2][4] = {};
    const int m0   = (tid >> 4) << 1;
    const int n0   = (tid & 15) << 2;
    const int arow = tid >> 3;
    const int acol = (tid & 7) << 2;
    const int brow = tid >> 4;
    const int bcol = (tid & 15) << 2;
    const int mg   = mblk * 32 + arow;
    const float* Asrc = p.ws + OFF_S;
    const float* W    = p.Ws + (size_t)gz * 512 * 512;

    for (int k0 = 0; k0 < 512; k0 += 32) {
        *(float4*)&As[arow][acol] = *(const float4*)(Asrc + (size_t)mg * 512 + k0 + acol);
        #pragma unroll
        for (int rr = 0; rr < 2; ++rr) {
            int krow = k0 + brow + rr * 16;
            int col  = nblk * 64 + bcol;
            *(float4*)&Bs[brow + rr * 16][bcol] = *(const float4*)(W + (size_t)krow * 512 + col);
        }
        __syncthreads();
        #pragma unroll
        for (int kk = 0; kk < 32; ++kk) {
            float a0 = As[m0][kk], a1 = As[m0 + 1][kk];
            float4 bv = *(float4*)&Bs[kk][n0];
            acc[0][0] = fmaf(a0, bv.x, acc[0][0]);
            acc[0][1] = fmaf(a0, bv.y, acc[0][1]);
            acc[0][2] = fmaf(a0, bv.z, acc[0][2]);
            acc[0][3] = fmaf(a0, bv.w, acc[0][3]);
            acc[1][0] = fmaf(a1, bv.x, acc[1][0]);
            acc[1][1] = fmaf(a1, bv.y, acc[1][1]);
            acc[1][2] = fmaf(a1, bv.z, acc[1][2]);
            acc[1][3] = fmaf(a1, bv.w, acc[1][3]);
        }
        __syncthreads();
    }
    #pragma unroll
    for (int r = 0; r < 2; ++r) {
        int b = mblk * 32 + m0 + r;
        #pragma unroll
        for (int j = 0; j < 4; ++j) {
            int n = nblk * 64 + n0 + j;
            size_t idx = OFF_PRE + (size_t)b * 2560 + (size_t)gz * 512 + n;
            p.ws[idx] = p.ws[idx] + acc[r][j] + p.bg[(size_t)gz * H_ + n];
        }
    }
}

// GEMM 3: A=hc [B,1024]; nblk<8: q = hc@Waq (K=1024); nblk>=8: hW = h_tilde@W_h (K=512)
__global__ __launch_bounds__(256) void k_g3(P p, int t)
{
    __shared__ float As[32][36];
    __shared__ float Bs[32][64];
    const int tid  = threadIdx.x;
    const int nblk = blockIdx.x, mblk = blockIdx.y;
    float acc[2][4] = {};
    const int m0   = (tid >> 4) << 1;
    const int n0   = (tid & 15) << 2;
    const int arow = tid >> 3;
    const int acol = (tid & 7) << 2;
    const int brow = tid >> 4;
    const int bcol = (tid & 15) << 2;
    const int mg   = mblk * 32 + arow;
    const float* Asrc = p.ws + OFF_HC;
    const int Kext = (nblk < 8) ? 1024 : 512;

    for (int k0 = 0; k0 < Kext; k0 += 32) {
        *(float4*)&As[arow][acol] = *(const float4*)(Asrc + (size_t)mg * 1024 + k0 + acol);
        #pragma unroll
        for (int rr = 0; rr < 2; ++rr) {
            int krow = k0 + brow + rr * 16;
            float4 bv;
            if (nblk < 8) bv = *(const float4*)(p.Waq + (size_t)krow * 512 + nblk * 64 + bcol);
            else          bv = *(const float4*)(p.W_h + (size_t)krow * 512 + (nblk - 8) * 64 + bcol);
            *(float4*)&Bs[brow + rr * 16][bcol] = bv;
        }
        __syncthreads();
        #pragma unroll
        for (int kk = 0; kk < 32; ++kk) {
            float a0 = As[m0][kk], a1 = As[m0 + 1][kk];
            float4 bv = *(float4*)&Bs[kk][n0];
            acc[0][0] = fmaf(a0, bv.x, acc[0][0]);
            acc[0][1] = fmaf(a0, bv.y, acc[0][1]);
            acc[0][2] = fmaf(a0, bv.z, acc[0][2]);
            acc[0][3] = fmaf(a0, bv.w, acc[0][3]);
            acc[1][0] = fmaf(a1, bv.x, acc[1][0]);
            acc[1][1] = fmaf(a1, bv.y, acc[1][1]);
            acc[1][2] = fmaf(a1, bv.z, acc[1][2]);
            acc[1][3] = fmaf(a1, bv.w, acc[1][3]);
        }
        __syncthreads();
    }
    #pragma unroll
    for (int r = 0; r < 2; ++r) {
        int b = mblk * 32 + m0 + r;
        #pragma unroll
        for (int j = 0; j < 4; ++j) {
            if (nblk < 8) {
                int n = nblk * 64 + n0 + j;
                p.ws[OFF_Q + (size_t)b * H_ + n] = acc[r][j];
            } else {
                int n = (nblk - 8) * 64 + n0 + j;
                p.ws[OFF_HW + (size_t)b * H_ + n] = acc[r][j];
            }
        }
    }
}

// GEMM 5: A=[e | g_t] (K=640), B=[W_e;W_g] -> h_t = tanh(acc + hW + bh); h, buf slot
__global__ __launch_bounds__(256) void k_g5(P p, int t)
{
    __shared__ float As[32][36];
    __shared__ float Bs[32][64];
    const int tid  = threadIdx.x;
    const int nblk = blockIdx.x, mblk = blockIdx.y;
    float acc[2][4] = {};
    const int m0   = (tid >> 4) << 1;
    const int n0   = (tid & 15) << 2;
    const int arow = tid >> 3;
    const int acol = (tid & 7) << 2;
    const int brow = tid >> 4;
    const int bcol = (tid & 15) << 2;
    const int mg   = mblk * 32 + arow;
    const float* Asrc = p.ws + OFF_E;

    for (int k0 = 0; k0 < 640; k0 += 32) {
        {
            int kg = k0 + acol;
            float4 av;
            if (kg < 512) av = *(const float4*)(Asrc + (size_t)mg * 512 + kg);
            else          av = *(const float4*)(p.g + ((size_t)mg * T_ + t) * D_ + (kg - 512));
            *(float4*)&As[arow][acol] = av;
        }
        #pragma unroll
        for (int rr = 0; rr < 2; ++rr) {
            int krow = k0 + brow + rr * 16;
            int col  = nblk * 64 + bcol;
            const float* s = (krow < 512) ? p.W_e + (size_t)krow * 512 + col
                                          : p.W_g + (size_t)(krow - 512) * 512 + col;
            *(float4*)&Bs[brow + rr * 16][bcol] = *(const float4*)s;
        }
        __syncthreads();
        #pragma unroll
        for (int kk = 0; kk < 32; ++kk) {
            float a0 = As[m0][kk], a1 = As[m0 + 1][kk];
            float4 bv = *(float4*)&Bs[kk][n0];
            acc[0][0] = fmaf(a0, bv.x, acc[0][0]);
            acc[0][1] = fmaf(a0, bv.y, acc[0][1]);
            acc[0][2] = fmaf(a0, bv.z, acc[0][2]);
            acc[0][3] = fmaf(a0, bv.w, acc[0][3]);
            acc[1][0] = fmaf(a1, bv.x, acc[1][0]);
            acc[1][1] = fmaf(a1, bv.y, acc[1][1]);
            acc[1][2] = fmaf(a1, bv.z, acc[1][2]);
            acc[1][3] = fmaf(a1, bv.w, acc[1][3]);
        }
        __syncthreads();
    }
    #pragma unroll
    for (int r = 0; r < 2; ++r) {
        int b = mblk * 32 + m0 + r;
        #pragma unroll
        for (int j = 0; j < 4; ++j) {
            int n = nblk * 64 + n0 + j;
            float hv = tanhf(acc[r][j] + p.ws[OFF_HW + (size_t)b * H_ + n] + p.bh[n]);
            p.ws[OFF_H + (size_t)b * H_ + n] = hv;
            p.ws[OFF_BUF + ((size_t)b * M_ + (t & (M_ - 1))) * H_ + n] = hv;
        }
    }
}

// gate combine: c_t, h_tilde from pre
__global__ __launch_bounds__(256) void k_comb(P p, int t)
{
    int idx = blockIdx.x * 256 + threadIdx.x;   // 65536 total
    int b = idx >> 9, n = idx & 511;
    const float* pre = p.ws + OFF_PRE + (size_t)b * 2560;
    float f  = sigf(pre[n]);
    float i  = sigf(pre[512 + n]);
    float Tt = sigf(pre[1024 + n]);
    float u  = tanhf(pre[1536 + n]);
    float o  = sigf(pre[2048 + n]);
    float cp = p.ws[OFF_HC + (size_t)b * 1024 + 512 + n];
    float s  = p.ws[OFF_S + (size_t)b * 512 + n];
    float c  = f * cp + i * u + Tt * s;
    float ht = o * tanhf(c);
    p.ws[OFF_HC + (size_t)b * 1024 + n] = ht;
    p.ws[OFF_HC + (size_t)b * 1024 + 512 + n] = c;
}

// attention over valid ring slots + logit of step t-1 (from h = h_{t-1})
__global__ __launch_bounds__(256) void k_attn(P p, int t)
{
    const int b = blockIdx.x;
    const int tid = threadIdx.x;
    const int lane = tid & 63, wv = tid >> 6;
    const int L = (t < M_) ? t : M_;
    __shared__ float sc[M_];
    __shared__ float al[M_];
    __shared__ float red[256];
    float* ws = p.ws;
    const float* qrow = ws + OFF_Q + (size_t)b * H_;

    for (int m = wv; m < L; m += 4) {
        int slot = (t - L + m) & (M_ - 1);
        const float* bw = ws + OFF_BUFW + ((size_t)b * M_ + slot) * H_;
        float pa = 0.f;
        for (int k = lane; k < H_; k += 64)
            pa += p.vt[k] * tanhf(qrow[k] + bw[k] + p.ba[k]);
        #pragma unroll
        for (int off = 32; off; off >>= 1) pa += __shfl_down(pa, off);
        if (lane == 0) sc[m] = pa;
    }
    // logit for t-1 (h still holds h_{t-1})
    {
        float pl = 0.f;
        const float* hrow = ws + OFF_H + (size_t)b * H_;
        for (int k = tid; k < H_; k += 256) pl += hrow[k] * p.Wcls[k];
        red[tid] = pl;
        __syncthreads();
        for (int s2 = 128; s2; s2 >>= 1) {
            if (tid < s2) red[tid] += red[tid + s2];
            __syncthreads();
        }
        if (tid == 0 && t > 0) p.out[(size_t)b * T_ + (t - 1)] = red[0] + p.bcls[0];
    }
    // softmax over valid slots
    float mx = -1e30f;
    for (int m = 0; m < L; ++m) mx = fmaxf(mx, sc[m]);
    if (tid < L) al[tid] = expf(sc[tid] - mx);
    __syncthreads();
    float sum = 0.f;
    for (int m = 0; m < L; ++m) sum += al[m];
    float inv = (L > 0) ? 1.f / sum : 0.f;
    for (int k = tid; k < H_; k += 256) {
        float acc = 0.f;
        for (int m = 0; m < L; ++m) {
            int slot = (t - L + m) & (M_ - 1);
            acc += al[m] * ws[OFF_BUF + ((size_t)b * M_ + slot) * H_ + k];
        }
        ws[OFF_E + (size_t)b * H_ + k] = acc * inv;
    }
}

// final logit (t = T-1)
__global__ __launch_bounds__(256) void k_fin(P p)
{
    int b = blockIdx.x, tid = threadIdx.x;
    __shared__ float red[256];
    const float* hrow = p.ws + OFF_H + (size_t)b * H_;
    float pl = 0.f;
    for (int k = tid; k < H_; k += 256) pl += hrow[k] * p.Wcls[k];
    red[tid] = pl;
    __syncthreads();
    for (int s2 = 128; s2; s2 >>= 1) {
        if (tid < s2) red[tid] += red[tid + s2];
        __syncthreads();
    }
    if (tid == 0) p.out[(size_t)b * T_ + (T_ - 1)] = red[0] + p.bcls[0];
}

// zero h and hc (ws is poisoned before every call)
__global__ __launch_bounds__(256) void k_zero(P p)
{
    size_t i = (size_t)blockIdx.x * 256 + threadIdx.x;
    if (i < 196608) p.ws[i] = 0.f;   // OFF_H(65536) + OFF_HC(131072) contiguous
}

extern "C" void kernel_launch(void* const* d_in, const int* in_sizes, int n_in,
                              void* d_out, int out_size, void* d_ws, size_t ws_size,
                              hipStream_t stream)
{
    (void)in_sizes; (void)n_in; (void)out_size; (void)ws_size;
    P p;
    p.ws   = (float*)d_ws;
    p.x    = (const float*)d_in[0];
    p.dlt  = (const float*)d_in[1];
    p.g    = (const float*)d_in[2];
    p.Wsh  = (const float*)d_in[3];
    p.Wsx  = (const float*)d_in[4];
    p.Wst  = (const float*)d_in[5];
    p.bs   = (const float*)d_in[6];
    p.Wh   = (const float*)d_in[7];
    p.Wx   = (const float*)d_in[8];
    p.Ws   = (const float*)d_in[9];
    p.bg   = (const float*)d_in[10];
    p.Waq  = (const float*)d_in[11];
    p.Wah  = (const float*)d_in[12];
    p.ba   = (const float*)d_in[13];
    p.vt   = (const float*)d_in[14];
    p.W_h  = (const float*)d_in[15];
    p.W_e  = (const float*)d_in[16];
    p.W_g  = (const float*)d_in[17];
    p.bh   = (const float*)d_in[18];
    p.Wcls = (const float*)d_in[19];
    p.bcls = (const float*)d_in[20];
    p.out  = (float*)d_out;

    k_zero<<<768, 256, 0, stream>>>(p);
    for (int t = 0; t < T_; ++t) {
        k_g1<<<dim3(56, 4), 256, 0, stream>>>(p, t);
        k_g2<<<dim3(8, 4, 5), 256, 0, stream>>>(p, t);
        k_comb<<<256, 256, 0, stream>>>(p, t);
        k_g3<<<dim3(16, 4), 256, 0, stream>>>(p, t);
        k_attn<<<128, 256, 0, stream>>>(p, t);
        k_g5<<<dim3(8, 4), 256, 0, stream>>>(p, t);
    }
    k_fin<<<128, 256, 0, stream>>>(p);
}